// Round 1
// baseline (4584.414 us; speedup 1.0000x reference)
//
#include <hip/hip_runtime.h>

#define TT 2048
#define BB 128
#define DD 128
#define HH 256

// ---------------------------------------------------------------------------
// Kernel 1: xproj[t,b,:] = x[t,b,:] @ W_in + b_in + b_h   (written to d_out)
// Rows R = T*B = 262144 flat. 64 rows per WG, 256 threads; thread = output col.
// W_in column lives in 128 VGPRs per thread; x tile staged in LDS (padded to
// 132 floats/row so broadcast float4 reads are conflict-free).
// ---------------------------------------------------------------------------
__global__ __launch_bounds__(256, 2) void xproj_kernel(
    const float* __restrict__ x, const float* __restrict__ W_in,
    const float* __restrict__ b_in, const float* __restrict__ b_h,
    float* __restrict__ out)
{
    __shared__ float xs[64 * 132];
    const int j = threadIdx.x;
    const long rowbase = (long)blockIdx.x * 64;

    // stage x tile [64][128] coalesced (float4)
    const float4* xg = (const float4*)(x + rowbase * DD);
    #pragma unroll
    for (int k = 0; k < 8; ++k) {
        int idx = j + k * 256;      // float4 index 0..2047
        int r   = idx >> 5;         // row 0..63
        int c4  = idx & 31;         // float4 col
        float4 v = xg[idx];
        *(float4*)&xs[r * 132 + c4 * 4] = v;
    }

    // this thread's W_in column -> registers (coalesced per d, L2-resident)
    float wreg[128];
    #pragma unroll
    for (int d = 0; d < 128; ++d) wreg[d] = W_in[d * HH + j];
    const float bias = b_in[j] + b_h[j];

    __syncthreads();

    float* outp = out + rowbase * HH + j;
    for (int r = 0; r < 64; ++r) {
        const float4* xr4 = (const float4*)&xs[r * 132];
        float a0 = 0.f, a1 = 0.f, a2 = 0.f, a3 = 0.f;
        #pragma unroll
        for (int q = 0; q < 8; ++q) {
            float4 v0 = xr4[q];
            float4 v1 = xr4[q + 8];
            float4 v2 = xr4[q + 16];
            float4 v3 = xr4[q + 24];
            a0 += v0.x * wreg[4*q+0]  + v0.y * wreg[4*q+1]  + v0.z * wreg[4*q+2]  + v0.w * wreg[4*q+3];
            a1 += v1.x * wreg[32+4*q] + v1.y * wreg[33+4*q] + v1.z * wreg[34+4*q] + v1.w * wreg[35+4*q];
            a2 += v2.x * wreg[64+4*q] + v2.y * wreg[65+4*q] + v2.z * wreg[66+4*q] + v2.w * wreg[67+4*q];
            a3 += v3.x * wreg[96+4*q] + v3.y * wreg[97+4*q] + v3.z * wreg[98+4*q] + v3.w * wreg[99+4*q];
        }
        outp[(long)r * HH] = ((a0 + a1) + (a2 + a3)) + bias;
    }
}

// ---------------------------------------------------------------------------
// Kernel 2: the sequential scan. One WG per batch element b (rows of h are
// independent!). 512 threads: thread (j = tid&255, half = tid>>8) computes
// the half-dot-product sum_k h[half*128+k] * W_h[half*128+k][j] with W_h in
// 128 VGPRs. h is broadcast via LDS (uniform-address float4 reads = free
// broadcast). 2 barriers/step. xp is read from d_out (written by kernel 1)
// and overwritten in place with h_t; per-thread 2-deep prefetch hides HBM.
// ---------------------------------------------------------------------------
__global__ __launch_bounds__(512, 2) void rnn_rec_kernel(
    const float* __restrict__ h0, const float* __restrict__ W_h,
    float* io)
{
    __shared__ float hbuf[2][HH];
    __shared__ float part[HH];
    const int tid  = threadIdx.x;
    const int j    = tid & (HH - 1);
    const int half = tid >> 8;
    const int b    = blockIdx.x;

    // W_h rows [half*128, half*128+128) of column j -> registers
    float w[128];
    #pragma unroll
    for (int k = 0; k < 128; ++k) w[k] = W_h[(half * 128 + k) * HH + j];

    if (half == 0) hbuf[0][j] = h0[b * HH + j];
    __syncthreads();

    float* xp = io + (long)b * HH + j;  // [t][b][j] at io + t*B*H
    float xp0 = 0.f, xp1 = 0.f;
    if (half == 0) {
        xp0 = xp[0];
        xp1 = xp[(long)BB * HH];
    }

    int cur = 0;
    for (int t = 0; t < TT; ++t) {
        const float4* h4 = (const float4*)&hbuf[cur][half * 128];
        float a0 = 0.f, a1 = 0.f, a2 = 0.f, a3 = 0.f;
        #pragma unroll
        for (int q = 0; q < 8; ++q) {
            float4 v0 = h4[q];
            float4 v1 = h4[q + 8];
            float4 v2 = h4[q + 16];
            float4 v3 = h4[q + 24];
            a0 += v0.x * w[4*q+0]  + v0.y * w[4*q+1]  + v0.z * w[4*q+2]  + v0.w * w[4*q+3];
            a1 += v1.x * w[32+4*q] + v1.y * w[33+4*q] + v1.z * w[34+4*q] + v1.w * w[35+4*q];
            a2 += v2.x * w[64+4*q] + v2.y * w[65+4*q] + v2.z * w[66+4*q] + v2.w * w[67+4*q];
            a3 += v3.x * w[96+4*q] + v3.y * w[97+4*q] + v3.z * w[98+4*q] + v3.w * w[99+4*q];
        }
        float p = (a0 + a1) + (a2 + a3);

        if (half == 1) part[j] = p;
        __syncthreads();

        if (half == 0) {
            float s = p + part[j] + xp0;
            // tanh(s) = 1 - 2/(exp(2s)+1); saturates correctly at +-inf
            float e   = __expf(2.f * s);
            float act = 1.f - 2.f / (e + 1.f);
            io[(long)t * BB * HH + (long)b * HH + j] = act;  // h_t overwrites xp_t
            hbuf[cur ^ 1][j] = act;
            xp0 = xp1;
            if (t + 2 < TT) xp1 = xp[(long)(t + 2) * BB * HH];
        }
        __syncthreads();
        cur ^= 1;
    }
}

extern "C" void kernel_launch(void* const* d_in, const int* in_sizes, int n_in,
                              void* d_out, int out_size, void* d_ws, size_t ws_size,
                              hipStream_t stream) {
    const float* x    = (const float*)d_in[0];
    const float* h0   = (const float*)d_in[1];
    const float* W_in = (const float*)d_in[2];
    const float* b_in = (const float*)d_in[3];
    const float* W_h  = (const float*)d_in[4];
    const float* b_h  = (const float*)d_in[5];
    float* out = (float*)d_out;

    // Phase 1: big parallel GEMM -> d_out holds xproj (+biases)
    xproj_kernel<<<(TT * BB) / 64, 256, 0, stream>>>(x, W_in, b_in, b_h, out);
    // Phase 2: sequential scan, overwrites d_out with h_t
    rnn_rec_kernel<<<BB, 512, 0, stream>>>(h0, W_h, out);
}

// Round 3
// 2935.956 us; speedup vs baseline: 1.5615x; 1.5615x over previous
//
#include <hip/hip_runtime.h>

#define TT 2048
#define BB 128
#define DD 128
#define HH 256

typedef float f32x4 __attribute__((ext_vector_type(4)));
typedef short s16x8 __attribute__((ext_vector_type(8)));
typedef short s16x4 __attribute__((ext_vector_type(4)));

static __device__ __forceinline__ unsigned short f2bf(float f) {
    unsigned u = __builtin_bit_cast(unsigned, f);
    u += 0x7fffu + ((u >> 16) & 1u);          // RNE
    return (unsigned short)(u >> 16);
}
static __device__ __forceinline__ float bf2f(unsigned short b) {
    unsigned u = ((unsigned)b) << 16;
    return __builtin_bit_cast(float, u);
}
static __device__ __forceinline__ float fast_tanh(float s) {
    // tanh(s) = 1 - 2/(exp(2s)+1); exp->inf and ->0 both saturate correctly
    float e = __expf(2.0f * s);
    float r = __builtin_amdgcn_rcpf(e + 1.0f);
    return __builtin_fmaf(-2.0f, r, 1.0f);
}

// ---------------------------------------------------------------------------
// xproj: out[t,b,:] = x[t,b,:] @ W_in + (b_in + b_h), via bf16 MFMA.
// W_in split hi+lo bf16 (error ~2^-17) static in VGPRs as B operand; x staged
// bf16 in XOR-swizzled LDS as A; bias as C-init. 64 rows/WG, 4 waves, wave w
// owns cols [w*64, w*64+64).
// Frag convention (consistent for A and B -> k-permutation cancels):
//   A: lane holds A[m = lane&15][k = kc*32 + (lane>>4)*8 + i]
//   B: lane holds B[k = kc*32 + (lane>>4)*8 + i][n = lane&15]
//   C/D: col = lane&15, row = (lane>>4)*4 + reg   (m89-verified)
// ---------------------------------------------------------------------------
__global__ __launch_bounds__(256, 2) void xproj_mfma(
    const float* __restrict__ x, const float* __restrict__ W_in,
    const float* __restrict__ b_in, const float* __restrict__ b_h,
    float* __restrict__ out)
{
    __shared__ short xs[64 * 128];  // bf16, swizzled, 16 KB
    const int tid  = threadIdx.x;
    const int lane = tid & 63;
    const int w    = tid >> 6;
    const int lrow = lane & 15;
    const int lgrp = lane >> 4;
    const long rbase = (long)blockIdx.x * 64;

    // B-frags: W_in[k][n], split hi/lo
    s16x8 bhi[4][4], blo[4][4];
    #pragma unroll
    for (int kc = 0; kc < 4; ++kc)
        #pragma unroll
        for (int nt = 0; nt < 4; ++nt) {
            const int n = w * 64 + nt * 16 + lrow;
            #pragma unroll
            for (int i = 0; i < 8; ++i) {
                float wv = W_in[(kc * 32 + lgrp * 8 + i) * HH + n];
                unsigned short h = f2bf(wv);
                bhi[kc][nt][i] = (short)h;
                blo[kc][nt][i] = (short)f2bf(wv - bf2f(h));
            }
        }
    float bias[4];
    #pragma unroll
    for (int nt = 0; nt < 4; ++nt) {
        const int n = w * 64 + nt * 16 + lrow;
        bias[nt] = b_in[n] + b_h[n];
    }

    // stage x tile [64 rows][128 k] -> bf16 LDS, byte ^= (row&7)<<4
    {
        const float4* xg = (const float4*)(x + rbase * DD);
        #pragma unroll
        for (int th = 0; th < 8; ++th) {
            int idx = tid + th * 256;       // float4 index, 2048 total
            int r   = idx >> 5;             // row
            int c4  = idx & 31;             // k/4
            float4 v = xg[idx];
            s16x4 p;
            p[0] = (short)f2bf(v.x); p[1] = (short)f2bf(v.y);
            p[2] = (short)f2bf(v.z); p[3] = (short)f2bf(v.w);
            unsigned off = (unsigned)(r * 256 + c4 * 8);
            off ^= (unsigned)((r & 7) << 4);
            *(s16x4*)((char*)xs + off) = p;
        }
    }
    __syncthreads();

    #pragma unroll
    for (int mt = 0; mt < 4; ++mt) {
        const int r = mt * 16 + lrow;
        s16x8 a[4];
        #pragma unroll
        for (int kc = 0; kc < 4; ++kc) {
            unsigned off = (unsigned)(r * 256 + kc * 64 + lgrp * 16);
            off ^= (unsigned)((r & 7) << 4);
            a[kc] = *(const s16x8*)((const char*)xs + off);
        }
        f32x4 acc[4];
        #pragma unroll
        for (int nt = 0; nt < 4; ++nt) { f32x4 c = {bias[nt], bias[nt], bias[nt], bias[nt]}; acc[nt] = c; }
        #pragma unroll
        for (int kc = 0; kc < 4; ++kc)
            #pragma unroll
            for (int nt = 0; nt < 4; ++nt)
                acc[nt] = __builtin_amdgcn_mfma_f32_16x16x32_bf16(a[kc], bhi[kc][nt], acc[nt], 0, 0, 0);
        #pragma unroll
        for (int kc = 0; kc < 4; ++kc)
            #pragma unroll
            for (int nt = 0; nt < 4; ++nt)
                acc[nt] = __builtin_amdgcn_mfma_f32_16x16x32_bf16(a[kc], blo[kc][nt], acc[nt], 0, 0, 0);
        #pragma unroll
        for (int nt = 0; nt < 4; ++nt)
            #pragma unroll
            for (int rr = 0; rr < 4; ++rr)
                out[(rbase + mt * 16 + lgrp * 4 + rr) * HH + w * 64 + nt * 16 + lrow] = acc[nt][rr];
    }
}

// ---------------------------------------------------------------------------
// Recurrence: 8 WGs x 16 batch rows, 4 waves, wave w owns h-cols [w*64,+64).
// D[j][g] = sum_k W_h[k][j] * h[g][k]  (A = W_h^T split hi/lo static in VGPRs,
// B = h bf16 in swizzled LDS double buffer). C-init = xproj (prefetched from
// d_out); tanh in fp32; h_t overwrites xp_t in d_out; 1 barrier/step.
// ---------------------------------------------------------------------------
struct RecCtx {
    float* io;
    int b0, lrow, lgrp, jb;
};

static __device__ __forceinline__ void rec_step(
    const RecCtx& c, int t,
    f32x4 (&xpu)[4], f32x4 (&xpp)[4],
    const short* curb, short* nxtb,
    const s16x8 (&whi)[4][8], const s16x8 (&wlo)[4][8])
{
    // prefetch next step's xp (C-init) while LDS h is consumed
    const int t1 = (t + 1 < TT) ? t + 1 : TT - 1;
    #pragma unroll
    for (int mt = 0; mt < 4; ++mt)
        xpp[mt] = *(const f32x4*)(c.io + ((long)t1 * BB + c.b0 + c.lrow) * HH + c.jb + mt * 16 + c.lgrp * 4);

    // B-frags: h[g = lane&15][k = kc*32 + lgrp*8 + i] from swizzled LDS
    s16x8 bbf[8];
    #pragma unroll
    for (int kc = 0; kc < 8; ++kc) {
        unsigned off = (unsigned)(c.lrow * 512 + kc * 64 + c.lgrp * 16);
        off ^= (unsigned)((c.lrow & 7) << 4);
        bbf[kc] = *(const s16x8*)((const char*)curb + off);
    }

    f32x4 acc[4];
    #pragma unroll
    for (int mt = 0; mt < 4; ++mt) acc[mt] = xpu[mt];
    #pragma unroll
    for (int kc = 0; kc < 8; ++kc)
        #pragma unroll
        for (int mt = 0; mt < 4; ++mt)
            acc[mt] = __builtin_amdgcn_mfma_f32_16x16x32_bf16(whi[mt][kc], bbf[kc], acc[mt], 0, 0, 0);
    #pragma unroll
    for (int kc = 0; kc < 8; ++kc)
        #pragma unroll
        for (int mt = 0; mt < 4; ++mt)
            acc[mt] = __builtin_amdgcn_mfma_f32_16x16x32_bf16(wlo[mt][kc], bbf[kc], acc[mt], 0, 0, 0);

    // tanh, write h_t to global (overwrites xp_t), write bf16 h to next LDS buf
    #pragma unroll
    for (int mt = 0; mt < 4; ++mt) {
        f32x4 hv;
        #pragma unroll
        for (int rr = 0; rr < 4; ++rr) hv[rr] = fast_tanh(acc[mt][rr]);
        *(f32x4*)(c.io + ((long)t * BB + c.b0 + c.lrow) * HH + c.jb + mt * 16 + c.lgrp * 4) = hv;
        s16x4 q;
        #pragma unroll
        for (int rr = 0; rr < 4; ++rr) q[rr] = (short)f2bf(hv[rr]);
        // D mapping: col g = lane&15 (the batch row), row j = jb + mt*16 + lgrp*4 + rr
        unsigned off = (unsigned)(c.lrow * 512 + (c.jb + mt * 16 + c.lgrp * 4) * 2);
        off ^= (unsigned)((c.lrow & 7) << 4);
        *(s16x4*)((char*)nxtb + off) = q;
    }
    __syncthreads();
}

__global__ __launch_bounds__(256, 1) void rnn_rec_mfma(
    const float* __restrict__ h0, const float* __restrict__ W_h,
    float* io)
{
    __shared__ short hb0[16 * 256];  // bf16 swizzled h, buffer 0 (8 KB)
    __shared__ short hb1[16 * 256];  // buffer 1
    const int tid  = threadIdx.x;
    const int lane = tid & 63;
    const int w    = tid >> 6;
    const int lrow = lane & 15;
    const int lgrp = lane >> 4;
    const int b0   = blockIdx.x * 16;
    const int jb   = w * 64;

    // A-frags: A[j][k] = W_h[k][j], j = jb + mt*16 + lrow, k = kc*32 + lgrp*8 + i
    s16x8 whi[4][8], wlo[4][8];
    #pragma unroll
    for (int mt = 0; mt < 4; ++mt) {
        const int j = jb + mt * 16 + lrow;
        #pragma unroll
        for (int kc = 0; kc < 8; ++kc)
            #pragma unroll
            for (int i = 0; i < 8; ++i) {
                float wv = W_h[(kc * 32 + lgrp * 8 + i) * HH + j];
                unsigned short h = f2bf(wv);
                whi[mt][kc][i] = (short)h;
                wlo[mt][kc][i] = (short)f2bf(wv - bf2f(h));
            }
    }

    // h_lds[0] <- h0 (fp32 -> bf16, swizzled); layout: [g][k], g = batch row
    {
        const int g  = tid >> 4;
        const int k0 = (tid & 15) * 16;
        const float* hp = h0 + (b0 + g) * HH + k0;
        #pragma unroll
        for (int cc = 0; cc < 2; ++cc) {
            s16x8 p;
            #pragma unroll
            for (int i = 0; i < 8; ++i) p[i] = (short)f2bf(hp[cc * 8 + i]);
            unsigned off = (unsigned)(g * 512 + k0 * 2 + cc * 16);
            off ^= (unsigned)((g & 7) << 4);
            *(s16x8*)((char*)hb0 + off) = p;
        }
    }

    RecCtx c{io, b0, lrow, lgrp, jb};

    // xp prefetch (C-init) for t=0
    f32x4 xa[4], xb[4];
    #pragma unroll
    for (int mt = 0; mt < 4; ++mt)
        xa[mt] = *(const f32x4*)(io + ((long)0 * BB + b0 + lrow) * HH + jb + mt * 16 + lgrp * 4);

    __syncthreads();

    for (int t = 0; t < TT; t += 2) {
        rec_step(c, t,     xa, xb, hb0, hb1, whi, wlo);
        rec_step(c, t + 1, xb, xa, hb1, hb0, whi, wlo);
    }
}

extern "C" void kernel_launch(void* const* d_in, const int* in_sizes, int n_in,
                              void* d_out, int out_size, void* d_ws, size_t ws_size,
                              hipStream_t stream) {
    const float* x    = (const float*)d_in[0];
    const float* h0   = (const float*)d_in[1];
    const float* W_in = (const float*)d_in[2];
    const float* b_in = (const float*)d_in[3];
    const float* W_h  = (const float*)d_in[4];
    const float* b_h  = (const float*)d_in[5];
    float* out = (float*)d_out;

    xproj_mfma<<<(TT * BB) / 64, 256, 0, stream>>>(x, W_in, b_in, b_h, out);
    rnn_rec_mfma<<<BB / 16, 256, 0, stream>>>(h0, W_h, out);
}

// Round 4
// 2067.259 us; speedup vs baseline: 2.2176x; 1.4202x over previous
//
#include <hip/hip_runtime.h>

#define TT 2048
#define BB 128
#define DD 128
#define HH 256

typedef float f32x4 __attribute__((ext_vector_type(4)));
typedef _Float16 f16x8 __attribute__((ext_vector_type(8)));
typedef _Float16 f16x4 __attribute__((ext_vector_type(4)));

static __device__ __forceinline__ float fast_tanh(float s) {
    // tanh(s) = 1 - 2/(exp(2s)+1); exp->inf and ->0 both saturate correctly
    float e = __expf(2.0f * s);
    float r = __builtin_amdgcn_rcpf(e + 1.0f);
    return __builtin_fmaf(-2.0f, r, 1.0f);
}

// LDS-only barrier: cross-wave communication in the rec loop is exclusively
// through LDS, so we drain lgkmcnt but NOT vmcnt (global h-stores / xp-loads
// are same-thread-same-address and may stay in flight across the barrier).
// sched_barrier(0) fences prevent hoisting of MFMAs/ds ops across it (rule #18).
static __device__ __forceinline__ void lds_barrier() {
    __builtin_amdgcn_sched_barrier(0);
    asm volatile("s_waitcnt lgkmcnt(0)" ::: "memory");
    __builtin_amdgcn_s_barrier();
    __builtin_amdgcn_sched_barrier(0);
}

// ---------------------------------------------------------------------------
// xproj: out[t,b,:] = x[t,b,:] @ W_in + (b_in + b_h), via f16 MFMA.
// W_in f16 static in VGPRs as B; x staged f16 in XOR-swizzled LDS as A; bias
// as C-init. 64 rows/WG, 4 waves, wave w owns cols [w*64, w*64+64).
// Frag convention (consistent for A and B -> k-permutation cancels):
//   A: lane holds A[m = lane&15][k = kc*32 + (lane>>4)*8 + i]
//   B: lane holds B[k = kc*32 + (lane>>4)*8 + i][n = lane&15]
//   C/D: col = lane&15, row = (lane>>4)*4 + reg   (m89-verified)
// ---------------------------------------------------------------------------
__global__ __launch_bounds__(256, 2) void xproj_mfma(
    const float* __restrict__ x, const float* __restrict__ W_in,
    const float* __restrict__ b_in, const float* __restrict__ b_h,
    float* __restrict__ out)
{
    __shared__ short xs[64 * 128];  // f16 bits, swizzled, 16 KB
    const int tid  = threadIdx.x;
    const int lane = tid & 63;
    const int w    = tid >> 6;
    const int lrow = lane & 15;
    const int lgrp = lane >> 4;
    const long rbase = (long)blockIdx.x * 64;

    // B-frags: W_in[k][n] as f16
    f16x8 bw[4][4];
    #pragma unroll
    for (int kc = 0; kc < 4; ++kc)
        #pragma unroll
        for (int nt = 0; nt < 4; ++nt) {
            const int n = w * 64 + nt * 16 + lrow;
            #pragma unroll
            for (int i = 0; i < 8; ++i)
                bw[kc][nt][i] = (_Float16)W_in[(kc * 32 + lgrp * 8 + i) * HH + n];
        }
    float bias[4];
    #pragma unroll
    for (int nt = 0; nt < 4; ++nt) {
        const int n = w * 64 + nt * 16 + lrow;
        bias[nt] = b_in[n] + b_h[n];
    }

    // stage x tile [64 rows][128 k] -> f16 LDS, byte ^= (row&7)<<4
    {
        const float4* xg = (const float4*)(x + rbase * DD);
        #pragma unroll
        for (int th = 0; th < 8; ++th) {
            int idx = tid + th * 256;       // float4 index, 2048 total
            int r   = idx >> 5;             // row
            int c4  = idx & 31;             // k/4
            float4 v = xg[idx];
            f16x4 p;
            p[0] = (_Float16)v.x; p[1] = (_Float16)v.y;
            p[2] = (_Float16)v.z; p[3] = (_Float16)v.w;
            unsigned off = (unsigned)(r * 256 + c4 * 8);
            off ^= (unsigned)((r & 7) << 4);
            *(f16x4*)((char*)xs + off) = p;
        }
    }
    __syncthreads();

    #pragma unroll
    for (int mt = 0; mt < 4; ++mt) {
        const int r = mt * 16 + lrow;
        f16x8 a[4];
        #pragma unroll
        for (int kc = 0; kc < 4; ++kc) {
            unsigned off = (unsigned)(r * 256 + kc * 64 + lgrp * 16);
            off ^= (unsigned)((r & 7) << 4);
            a[kc] = *(const f16x8*)((const char*)xs + off);
        }
        f32x4 acc[4];
        #pragma unroll
        for (int nt = 0; nt < 4; ++nt) { f32x4 c = {bias[nt], bias[nt], bias[nt], bias[nt]}; acc[nt] = c; }
        #pragma unroll
        for (int kc = 0; kc < 4; ++kc)
            #pragma unroll
            for (int nt = 0; nt < 4; ++nt)
                acc[nt] = __builtin_amdgcn_mfma_f32_16x16x32_f16(a[kc], bw[kc][nt], acc[nt], 0, 0, 0);
        #pragma unroll
        for (int nt = 0; nt < 4; ++nt)
            #pragma unroll
            for (int rr = 0; rr < 4; ++rr)
                out[(rbase + mt * 16 + lgrp * 4 + rr) * HH + w * 64 + nt * 16 + lrow] = acc[nt][rr];
    }
}

// ---------------------------------------------------------------------------
// Recurrence: 8 WGs x 16 batch rows, 4 waves, wave w owns h-cols [w*64,+64).
// D[j][g] = sum_k W_h[k][j] * h[g][k]; A = W_h^T f16 static in VGPRs (128),
// B = h f16 in swizzled LDS double buffer. C-init = xproj (prefetched 2 steps
// ahead from d_out); tanh fp32; h_t overwrites xp_t; 1 lgkm-only barrier/step.
// ---------------------------------------------------------------------------
struct RecCtx {
    float* io;
    int b0, lrow, lgrp, jb;
};

static __device__ __forceinline__ void rec_step(
    const RecCtx& c, int t,
    f32x4 (&xp)[4],                 // in: C-init for step t; out: prefetched t+2
    const short* curb, short* nxtb,
    const f16x8 (&wh)[4][8])
{
    // B-frags: h[g = lane&15][k = kc*32 + lgrp*8 + i] from swizzled LDS
    f16x8 bbf[8];
    #pragma unroll
    for (int kc = 0; kc < 8; ++kc) {
        unsigned off = (unsigned)(c.lrow * 512 + kc * 64 + c.lgrp * 16);
        off ^= (unsigned)((c.lrow & 7) << 4);
        bbf[kc] = *(const f16x8*)((const char*)curb + off);
    }

    // C-init from the 2-steps-ago prefetch, then refill xp with t+2's data
    f32x4 acc[4];
    #pragma unroll
    for (int mt = 0; mt < 4; ++mt) acc[mt] = xp[mt];
    const int t2 = (t + 2 < TT) ? t + 2 : TT - 1;
    #pragma unroll
    for (int mt = 0; mt < 4; ++mt)
        xp[mt] = *(const f32x4*)(c.io + ((long)t2 * BB + c.b0 + c.lrow) * HH + c.jb + mt * 16 + c.lgrp * 4);

    // 4 independent chains x 8 deep
    #pragma unroll
    for (int kc = 0; kc < 8; ++kc)
        #pragma unroll
        for (int mt = 0; mt < 4; ++mt)
            acc[mt] = __builtin_amdgcn_mfma_f32_16x16x32_f16(wh[mt][kc], bbf[kc], acc[mt], 0, 0, 0);

    // tanh, store h_t to global (overwrites xp_t), write f16 h to next LDS buf
    #pragma unroll
    for (int mt = 0; mt < 4; ++mt) {
        f32x4 hv;
        #pragma unroll
        for (int rr = 0; rr < 4; ++rr) hv[rr] = fast_tanh(acc[mt][rr]);
        *(f32x4*)(c.io + ((long)t * BB + c.b0 + c.lrow) * HH + c.jb + mt * 16 + c.lgrp * 4) = hv;
        f16x4 q;
        #pragma unroll
        for (int rr = 0; rr < 4; ++rr) q[rr] = (_Float16)hv[rr];
        // D mapping: col g = lane&15 (batch row), row j = jb + mt*16 + lgrp*4 + rr
        unsigned off = (unsigned)(c.lrow * 512 + (c.jb + mt * 16 + c.lgrp * 4) * 2);
        off ^= (unsigned)((c.lrow & 7) << 4);
        *(f16x4*)((char*)nxtb + off) = q;
    }
    lds_barrier();
}

__global__ __launch_bounds__(256, 1) void rnn_rec_mfma(
    const float* __restrict__ h0, const float* __restrict__ W_h,
    float* io)
{
    __shared__ short hb0[16 * 256];  // f16 swizzled h, buffer 0 (8 KB)
    __shared__ short hb1[16 * 256];  // buffer 1
    const int tid  = threadIdx.x;
    const int lane = tid & 63;
    const int w    = tid >> 6;
    const int lrow = lane & 15;
    const int lgrp = lane >> 4;
    const int b0   = blockIdx.x * 16;
    const int jb   = w * 64;

    // A-frags: A[j][k] = W_h[k][j], j = jb + mt*16 + lrow, k = kc*32 + lgrp*8 + i
    f16x8 wh[4][8];
    #pragma unroll
    for (int mt = 0; mt < 4; ++mt) {
        const int j = jb + mt * 16 + lrow;
        #pragma unroll
        for (int kc = 0; kc < 8; ++kc)
            #pragma unroll
            for (int i = 0; i < 8; ++i)
                wh[mt][kc][i] = (_Float16)W_h[(kc * 32 + lgrp * 8 + i) * HH + j];
    }

    // h_lds[0] <- h0 (fp32 -> f16, swizzled); layout: [g][k], g = batch row
    {
        const int g  = tid >> 4;
        const int k0 = (tid & 15) * 16;
        const float* hp = h0 + (b0 + g) * HH + k0;
        #pragma unroll
        for (int cc = 0; cc < 2; ++cc) {
            f16x8 p;
            #pragma unroll
            for (int i = 0; i < 8; ++i) p[i] = (_Float16)hp[cc * 8 + i];
            unsigned off = (unsigned)(g * 512 + k0 * 2 + cc * 16);
            off ^= (unsigned)((g & 7) << 4);
            *(f16x8*)((char*)hb0 + off) = p;
        }
    }

    RecCtx c{io, b0, lrow, lgrp, jb};

    // xp prefetch (C-init) for t=0 and t=1 (prefetch distance 2, parity slots)
    f32x4 xa[4], xb[4];
    #pragma unroll
    for (int mt = 0; mt < 4; ++mt) {
        xa[mt] = *(const f32x4*)(io + ((long)0 * BB + b0 + lrow) * HH + jb + mt * 16 + lgrp * 4);
        xb[mt] = *(const f32x4*)(io + ((long)1 * BB + b0 + lrow) * HH + jb + mt * 16 + lgrp * 4);
    }

    __syncthreads();

    for (int t = 0; t < TT; t += 2) {
        rec_step(c, t,     xa, hb0, hb1, wh);
        rec_step(c, t + 1, xb, hb1, hb0, wh);
    }
}

extern "C" void kernel_launch(void* const* d_in, const int* in_sizes, int n_in,
                              void* d_out, int out_size, void* d_ws, size_t ws_size,
                              hipStream_t stream) {
    const float* x    = (const float*)d_in[0];
    const float* h0   = (const float*)d_in[1];
    const float* W_in = (const float*)d_in[2];
    const float* b_in = (const float*)d_in[3];
    const float* W_h  = (const float*)d_in[4];
    const float* b_h  = (const float*)d_in[5];
    float* out = (float*)d_out;

    xproj_mfma<<<(TT * BB) / 64, 256, 0, stream>>>(x, W_in, b_in, b_h, out);
    rnn_rec_mfma<<<BB / 16, 256, 0, stream>>>(h0, W_h, out);
}

// Round 5
// 2059.831 us; speedup vs baseline: 2.2256x; 1.0036x over previous
//
#include <hip/hip_runtime.h>

#define TT 2048
#define BB 128
#define DD 128
#define HH 256

typedef float f32x4 __attribute__((ext_vector_type(4)));
typedef _Float16 f16x8 __attribute__((ext_vector_type(8)));
typedef _Float16 f16x4 __attribute__((ext_vector_type(4)));

static __device__ __forceinline__ float fast_tanh(float s) {
    // tanh(s) = 1 - 2/(exp(2s)+1); exp->inf and ->0 both saturate correctly
    float e = __expf(2.0f * s);
    float r = __builtin_amdgcn_rcpf(e + 1.0f);
    return __builtin_fmaf(-2.0f, r, 1.0f);
}

// LDS-only barrier: cross-wave communication in the rec loop is exclusively
// through LDS, so drain lgkmcnt but NOT vmcnt (global h-stores / xp-loads are
// same-thread-same-address and stay in flight across the barrier).
// sched_barrier(0) fences prevent hoisting across it (rule #18).
static __device__ __forceinline__ void lds_barrier() {
    __builtin_amdgcn_sched_barrier(0);
    asm volatile("s_waitcnt lgkmcnt(0)" ::: "memory");
    __builtin_amdgcn_s_barrier();
    __builtin_amdgcn_sched_barrier(0);
}

// ---------------------------------------------------------------------------
// xproj: out[t,b,:] = x[t,b,:] @ W_in + (b_in + b_h), via f16 MFMA.
// (unchanged from round 4 — ~100 us, ~3.8 TB/s, 5% of total)
// ---------------------------------------------------------------------------
__global__ __launch_bounds__(256, 2) void xproj_mfma(
    const float* __restrict__ x, const float* __restrict__ W_in,
    const float* __restrict__ b_in, const float* __restrict__ b_h,
    float* __restrict__ out)
{
    __shared__ short xs[64 * 128];  // f16 bits, swizzled, 16 KB
    const int tid  = threadIdx.x;
    const int lane = tid & 63;
    const int w    = tid >> 6;
    const int lrow = lane & 15;
    const int lgrp = lane >> 4;
    const long rbase = (long)blockIdx.x * 64;

    f16x8 bw[4][4];
    #pragma unroll
    for (int kc = 0; kc < 4; ++kc)
        #pragma unroll
        for (int nt = 0; nt < 4; ++nt) {
            const int n = w * 64 + nt * 16 + lrow;
            #pragma unroll
            for (int i = 0; i < 8; ++i)
                bw[kc][nt][i] = (_Float16)W_in[(kc * 32 + lgrp * 8 + i) * HH + n];
        }
    float bias[4];
    #pragma unroll
    for (int nt = 0; nt < 4; ++nt) {
        const int n = w * 64 + nt * 16 + lrow;
        bias[nt] = b_in[n] + b_h[n];
    }

    {
        const float4* xg = (const float4*)(x + rbase * DD);
        #pragma unroll
        for (int th = 0; th < 8; ++th) {
            int idx = tid + th * 256;
            int r   = idx >> 5;
            int c4  = idx & 31;
            float4 v = xg[idx];
            f16x4 p;
            p[0] = (_Float16)v.x; p[1] = (_Float16)v.y;
            p[2] = (_Float16)v.z; p[3] = (_Float16)v.w;
            unsigned off = (unsigned)(r * 256 + c4 * 8);
            off ^= (unsigned)((r & 7) << 4);
            *(f16x4*)((char*)xs + off) = p;
        }
    }
    __syncthreads();

    #pragma unroll
    for (int mt = 0; mt < 4; ++mt) {
        const int r = mt * 16 + lrow;
        f16x8 a[4];
        #pragma unroll
        for (int kc = 0; kc < 4; ++kc) {
            unsigned off = (unsigned)(r * 256 + kc * 64 + lgrp * 16);
            off ^= (unsigned)((r & 7) << 4);
            a[kc] = *(const f16x8*)((const char*)xs + off);
        }
        f32x4 acc[4];
        #pragma unroll
        for (int nt = 0; nt < 4; ++nt) { f32x4 c = {bias[nt], bias[nt], bias[nt], bias[nt]}; acc[nt] = c; }
        #pragma unroll
        for (int kc = 0; kc < 4; ++kc)
            #pragma unroll
            for (int nt = 0; nt < 4; ++nt)
                acc[nt] = __builtin_amdgcn_mfma_f32_16x16x32_f16(a[kc], bw[kc][nt], acc[nt], 0, 0, 0);
        #pragma unroll
        for (int nt = 0; nt < 4; ++nt)
            #pragma unroll
            for (int rr = 0; rr < 4; ++rr)
                out[(rbase + mt * 16 + lgrp * 4 + rr) * HH + w * 64 + nt * 16 + lrow] = acc[nt][rr];
    }
}

// ---------------------------------------------------------------------------
// Recurrence: 8 WGs x 16 batch rows; 512 threads = 8 waves (2/SIMD); wave w
// owns h-cols [w*32, w*32+32).  D[j][g] = sum_k W_h[k][j] * h[g][k];
// A = W_h^T f16 static in VGPRs (32/lane), B = h f16 in swizzled LDS dbuf.
// K-split: k<128 -> accA (init xp), k>=128 -> accB (init 0), merged by add:
// 4 independent 4-deep MFMA chains per wave (8/SIMD) to cover MFMA latency.
// C-init = xproj prefetched 2 steps ahead; tanh fp32; h_t overwrites xp_t;
// 1 lgkm-only barrier/step; setprio(1) around the MFMA cluster (T5).
// ---------------------------------------------------------------------------
struct RecCtx {
    float* io;
    int b0, lrow, lgrp, jb;
};

static __device__ __forceinline__ void rec_step(
    const RecCtx& c, int t,
    f32x4 (&xp)[2],                 // in: C-init for step t; out: prefetched t+2
    const short* curb, short* nxtb,
    const f16x8 (&wh)[2][8])
{
    // issue next-next xp load FIRST (T14: issue-early; consumed 2 steps later)
    f32x4 xpn[2];
    const int t2 = (t + 2 < TT) ? t + 2 : TT - 1;
    #pragma unroll
    for (int mt = 0; mt < 2; ++mt)
        xpn[mt] = *(const f32x4*)(c.io + ((long)t2 * BB + c.b0 + c.lrow) * HH + c.jb + mt * 16 + c.lgrp * 4);

    // B-frags: h[g = lane&15][k = kc*32 + lgrp*8 + i] from swizzled LDS
    f16x8 bbf[8];
    #pragma unroll
    for (int kc = 0; kc < 8; ++kc) {
        unsigned off = (unsigned)(c.lrow * 512 + kc * 64 + c.lgrp * 16);
        off ^= (unsigned)((c.lrow & 7) << 4);
        bbf[kc] = *(const f16x8*)((const char*)curb + off);
    }

    f32x4 accA[2], accB[2];
    #pragma unroll
    for (int mt = 0; mt < 2; ++mt) {
        accA[mt] = xp[mt];
        f32x4 z = {0.f, 0.f, 0.f, 0.f};
        accB[mt] = z;
        xp[mt] = xpn[mt];
    }

    __builtin_amdgcn_s_setprio(1);
    #pragma unroll
    for (int kc = 0; kc < 4; ++kc)
        #pragma unroll
        for (int mt = 0; mt < 2; ++mt) {
            accA[mt] = __builtin_amdgcn_mfma_f32_16x16x32_f16(wh[mt][kc],     bbf[kc],     accA[mt], 0, 0, 0);
            accB[mt] = __builtin_amdgcn_mfma_f32_16x16x32_f16(wh[mt][kc + 4], bbf[kc + 4], accB[mt], 0, 0, 0);
        }
    __builtin_amdgcn_s_setprio(0);

    // tanh, store h_t to global (overwrites xp_t), write f16 h to next LDS buf
    #pragma unroll
    for (int mt = 0; mt < 2; ++mt) {
        f32x4 s4 = accA[mt] + accB[mt];
        f32x4 hv;
        #pragma unroll
        for (int rr = 0; rr < 4; ++rr) hv[rr] = fast_tanh(s4[rr]);
        *(f32x4*)(c.io + ((long)t * BB + c.b0 + c.lrow) * HH + c.jb + mt * 16 + c.lgrp * 4) = hv;
        f16x4 q;
        #pragma unroll
        for (int rr = 0; rr < 4; ++rr) q[rr] = (_Float16)hv[rr];
        // D mapping: col g = lane&15 (batch row), row j = jb + mt*16 + lgrp*4 + rr
        unsigned off = (unsigned)(c.lrow * 512 + (c.jb + mt * 16 + c.lgrp * 4) * 2);
        off ^= (unsigned)((c.lrow & 7) << 4);
        *(f16x4*)((char*)nxtb + off) = q;
    }
    lds_barrier();
}

__global__ __launch_bounds__(512, 2) void rnn_rec_mfma(
    const float* __restrict__ h0, const float* __restrict__ W_h,
    float* io)
{
    __shared__ short hb0[16 * 256];  // f16 swizzled h, buffer 0 (8 KB)
    __shared__ short hb1[16 * 256];  // buffer 1
    const int tid  = threadIdx.x;
    const int lane = tid & 63;
    const int w    = tid >> 6;       // 0..7
    const int lrow = lane & 15;
    const int lgrp = lane >> 4;
    const int b0   = blockIdx.x * 16;
    const int jb   = w * 32;

    // A-frags: A[j][k] = W_h[k][j], j = jb + mt*16 + lrow, k = kc*32 + lgrp*8 + i
    f16x8 wh[2][8];
    #pragma unroll
    for (int mt = 0; mt < 2; ++mt) {
        const int j = jb + mt * 16 + lrow;
        #pragma unroll
        for (int kc = 0; kc < 8; ++kc)
            #pragma unroll
            for (int i = 0; i < 8; ++i)
                wh[mt][kc][i] = (_Float16)W_h[(kc * 32 + lgrp * 8 + i) * HH + j];
    }

    // h_lds[0] <- h0 (fp32 -> f16, swizzled); layout: [g][k], g = batch row
    {
        const int g  = tid >> 5;            // 0..15
        const int k0 = (tid & 31) * 8;      // 8 f16 per thread
        const float* hp = h0 + (b0 + g) * HH + k0;
        f16x8 p;
        #pragma unroll
        for (int i = 0; i < 8; ++i) p[i] = (_Float16)hp[i];
        unsigned off = (unsigned)(g * 512 + k0 * 2);
        off ^= (unsigned)((g & 7) << 4);
        *(f16x8*)((char*)hb0 + off) = p;
    }

    RecCtx c{io, b0, lrow, lgrp, jb};

    // xp prefetch (C-init) for t=0 and t=1 (prefetch distance 2, parity slots)
    f32x4 xa[2], xb[2];
    #pragma unroll
    for (int mt = 0; mt < 2; ++mt) {
        xa[mt] = *(const f32x4*)(io + ((long)0 * BB + b0 + lrow) * HH + jb + mt * 16 + lgrp * 4);
        xb[mt] = *(const f32x4*)(io + ((long)1 * BB + b0 + lrow) * HH + jb + mt * 16 + lgrp * 4);
    }

    __syncthreads();

    for (int t = 0; t < TT; t += 2) {
        rec_step(c, t,     xa, hb0, hb1, wh);
        rec_step(c, t + 1, xb, hb1, hb0, wh);
    }
}

extern "C" void kernel_launch(void* const* d_in, const int* in_sizes, int n_in,
                              void* d_out, int out_size, void* d_ws, size_t ws_size,
                              hipStream_t stream) {
    const float* x    = (const float*)d_in[0];
    const float* h0   = (const float*)d_in[1];
    const float* W_in = (const float*)d_in[2];
    const float* b_in = (const float*)d_in[3];
    const float* W_h  = (const float*)d_in[4];
    const float* b_h  = (const float*)d_in[5];
    float* out = (float*)d_out;

    xproj_mfma<<<(TT * BB) / 64, 256, 0, stream>>>(x, W_in, b_in, b_h, out);
    rnn_rec_mfma<<<BB / 16, 512, 0, stream>>>(h0, W_h, out);
}